// Round 1
// baseline (207.022 us; speedup 1.0000x reference)
//
#include <hip/hip_runtime.h>
#include <hip/hip_bf16.h>
#include <stdint.h>

#define B_  8
#define T_  2048
#define E_  512

typedef __attribute__((ext_vector_type(8))) __bf16 bf16x8;
typedef __attribute__((ext_vector_type(8))) unsigned short ushort8;
typedef __attribute__((ext_vector_type(4))) float f32x4;

__device__ __forceinline__ float bf2f(unsigned short u) {
  union { unsigned int u; float f; } c; c.u = ((unsigned int)u) << 16; return c.f;
}
// round-to-nearest-even f32 -> bf16 (finite inputs)
__device__ __forceinline__ unsigned short f2bf(float f) {
  union { float f; unsigned int u; } c; c.f = f;
  unsigned int u = c.u;
  unsigned int r = (u + 0x7FFFu + ((u >> 16) & 1u)) >> 16;
  return (unsigned short)r;
}

__device__ __forceinline__ void gload_lds16(const void* g, void* l) {
  __builtin_amdgcn_global_load_lds(
      (const __attribute__((address_space(1))) uint32_t*)g,
      (__attribute__((address_space(3))) uint32_t*)l, 16, 0, 0);
}

// ---------------- conversion kernels ----------------

__global__ __launch_bounds__(256)
void conv_x_kernel(const float* __restrict__ x, unsigned short* __restrict__ xb) {
  size_t i = ((size_t)blockIdx.x * 256 + threadIdx.x) * 8;
  float4 f0 = *reinterpret_cast<const float4*>(x + i);
  float4 f1 = *reinterpret_cast<const float4*>(x + i + 4);
  ushort8 r;
  r[0] = f2bf(f0.x); r[1] = f2bf(f0.y); r[2] = f2bf(f0.z); r[3] = f2bf(f0.w);
  r[4] = f2bf(f1.x); r[5] = f2bf(f1.y); r[6] = f2bf(f1.z); r[7] = f2bf(f1.w);
  *reinterpret_cast<ushort8*>(xb + i) = r;
}

// WT[n][kk] = (n<512 ? Wq[kk][n]*scale : Wk[kk][n-512]);  bqk[n] = (n<512? bq[n]*scale : bk[n-512])
__global__ __launch_bounds__(256)
void conv_w_kernel(const float* __restrict__ Wq, const float* __restrict__ Wk,
                   const float* __restrict__ bq, const float* __restrict__ bk,
                   unsigned short* __restrict__ WT, float* __restrict__ bqk, float scale) {
  int idx = blockIdx.x * 256 + threadIdx.x;      // 0 .. 2*512*512-1
  int n  = idx >> 9;
  int kk = idx & 511;
  float v = (n < E_) ? Wq[kk * E_ + n] * scale : Wk[kk * E_ + (n - E_)];
  WT[idx] = f2bf(v);
  if (idx < 2 * E_) {
    float bv = (idx < E_) ? bq[idx] * scale : bk[idx - E_];
    bqk[idx] = bv;
  }
}

// xT[b][e][t] = bf16(x[b][t][e])
__global__ __launch_bounds__(256)
void trans_x_kernel(const float* __restrict__ x, unsigned short* __restrict__ xT) {
  __shared__ unsigned short tile[64][66];
  const int t0 = blockIdx.x * 64, e0 = blockIdx.y * 64, b = blockIdx.z;
  const int tid = threadIdx.x;
  const float* xb = x + ((size_t)b * T_ + t0) * E_ + e0;
#pragma unroll
  for (int it = 0; it < 4; ++it) {
    int tr = (tid >> 4) + it * 16;
    int ec = (tid & 15) * 4;
    float4 f = *reinterpret_cast<const float4*>(xb + (size_t)tr * E_ + ec);
    tile[ec + 0][tr] = f2bf(f.x);
    tile[ec + 1][tr] = f2bf(f.y);
    tile[ec + 2][tr] = f2bf(f.z);
    tile[ec + 3][tr] = f2bf(f.w);
  }
  __syncthreads();
  unsigned short* dst = xT + ((size_t)b * E_ + e0) * T_ + t0;
#pragma unroll
  for (int it = 0; it < 2; ++it) {
    int er = (tid >> 3) + it * 32;
    int tg = (tid & 7) * 8;
    ushort8 r;
#pragma unroll
    for (int j = 0; j < 8; ++j) r[j] = tile[er][tg + j];
    *reinterpret_cast<ushort8*>(dst + (size_t)er * T_ + tg) = r;
  }
}

// ---------------- GEMM: C[M,N] = A[M,K] @ B'[N,K]^T, bf16 in, f32 acc ----------------
// BM=BN=128, BK=32, 256 threads (4 waves in 2x2), m97-style global_load_lds staging.
template<int OUT_BF16>
__global__ __launch_bounds__(256)
void gemm_bt(const unsigned short* __restrict__ A, int lda, long long strA,
             const unsigned short* __restrict__ B, int ldb, long long strB,
             void* __restrict__ Cv, int ldc, long long strC,
             int K, const float* __restrict__ bias)
{
  __shared__ unsigned short sA[128 * 32];
  __shared__ unsigned short sB[128 * 32];
  const int tid  = threadIdx.x;
  const int lane = tid & 63;
  const int wv   = tid >> 6;
  const int wr   = wv >> 1;
  const int wc   = wv & 1;
  const long long m0 = (long long)blockIdx.y * 128;
  const long long n0 = (long long)blockIdx.x * 128;
  const unsigned short* Ab = A + (long long)blockIdx.z * strA + m0 * lda;
  const unsigned short* Bb = B + (long long)blockIdx.z * strB + n0 * ldb;

  f32x4 acc[4][4];
#pragma unroll
  for (int i = 0; i < 4; ++i)
#pragma unroll
    for (int j = 0; j < 4; ++j) acc[i][j] = (f32x4){0.f, 0.f, 0.f, 0.f};

  const int srow = lane >> 2;        // staging row within 16-row chunk
  const int ke   = (lane & 3) * 8;   // staging k-element offset (16B)
  const int fr   = lane & 15;
  const int fo   = (lane >> 4) * 8;

  const int nsteps = K >> 5;
  for (int kt = 0; kt < nsteps; ++kt) {
    const int kbase = kt * 32;
#pragma unroll
    for (int it = 0; it < 2; ++it) {
      const int c   = it * 4 + wv;     // chunk 0..7 (1KB each)
      const int row = c * 16 + srow;   // 0..127
      gload_lds16(Ab + (long long)row * lda + kbase + ke, &sA[c * 512]);
      gload_lds16(Bb + (long long)row * ldb + kbase + ke, &sB[c * 512]);
    }
    __syncthreads();
    bf16x8 af[4], bfv[4];
#pragma unroll
    for (int m = 0; m < 4; ++m)
      af[m] = *reinterpret_cast<const bf16x8*>(&sA[(wr * 64 + m * 16 + fr) * 32 + fo]);
#pragma unroll
    for (int n = 0; n < 4; ++n)
      bfv[n] = *reinterpret_cast<const bf16x8*>(&sB[(wc * 64 + n * 16 + fr) * 32 + fo]);
#pragma unroll
    for (int m = 0; m < 4; ++m)
#pragma unroll
      for (int n = 0; n < 4; ++n)
        acc[m][n] = __builtin_amdgcn_mfma_f32_16x16x32_bf16(af[m], bfv[n], acc[m][n], 0, 0, 0);
    __syncthreads();
  }

  const int rq = (lane >> 4) * 4;
  if (bias) {
#pragma unroll
    for (int n = 0; n < 4; ++n) {
      const float bv = bias[n0 + wc * 64 + n * 16 + fr];
#pragma unroll
      for (int m = 0; m < 4; ++m)
#pragma unroll
        for (int j = 0; j < 4; ++j) acc[m][n][j] += bv;
    }
  }
  if (OUT_BF16) {
    unsigned short* C = (unsigned short*)Cv + (long long)blockIdx.z * strC;
#pragma unroll
    for (int m = 0; m < 4; ++m)
#pragma unroll
      for (int j = 0; j < 4; ++j) {
        const long long row = m0 + wr * 64 + m * 16 + rq + j;
#pragma unroll
        for (int n = 0; n < 4; ++n) {
          const long long col = n0 + wc * 64 + n * 16 + fr;
          C[row * ldc + col] = f2bf(acc[m][n][j]);
        }
      }
  } else {
    float* C = (float*)Cv + (long long)blockIdx.z * strC;
#pragma unroll
    for (int m = 0; m < 4; ++m)
#pragma unroll
      for (int j = 0; j < 4; ++j) {
        const long long row = m0 + wr * 64 + m * 16 + rq + j;
#pragma unroll
        for (int n = 0; n < 4; ++n) {
          const long long col = n0 + wc * 64 + n * 16 + fr;
          C[row * ldc + col] = acc[m][n][j];
        }
      }
  }
}

// ---------------- row softmax over 2048 cols, one wave per row, in-place bf16 ----------------
__global__ __launch_bounds__(256)
void softmax_kernel(unsigned short* __restrict__ attn) {
  const int row  = blockIdx.x * 4 + (threadIdx.x >> 6);
  const int lane = threadIdx.x & 63;
  unsigned short* p = attn + (size_t)row * T_;

  float v[32];
#pragma unroll
  for (int c = 0; c < 4; ++c) {
    ushort8 s = *reinterpret_cast<const ushort8*>(p + c * 512 + lane * 8);
#pragma unroll
    for (int j = 0; j < 8; ++j) v[c * 8 + j] = bf2f(s[j]);
  }
  float mx = v[0];
#pragma unroll
  for (int i = 1; i < 32; ++i) mx = fmaxf(mx, v[i]);
#pragma unroll
  for (int o = 32; o > 0; o >>= 1) mx = fmaxf(mx, __shfl_xor(mx, o));

  float sum = 0.f;
#pragma unroll
  for (int i = 0; i < 32; ++i) { v[i] = __expf(v[i] - mx); sum += v[i]; }
#pragma unroll
  for (int o = 32; o > 0; o >>= 1) sum += __shfl_xor(sum, o);
  const float inv = 1.0f / sum;

#pragma unroll
  for (int c = 0; c < 4; ++c) {
    ushort8 r;
#pragma unroll
    for (int j = 0; j < 8; ++j) r[j] = f2bf(v[c * 8 + j] * inv);
    *reinterpret_cast<ushort8*>(p + c * 512 + lane * 8) = r;
  }
}

// ---------------- launch ----------------
extern "C" void kernel_launch(void* const* d_in, const int* in_sizes, int n_in,
                              void* d_out, int out_size, void* d_ws, size_t ws_size,
                              hipStream_t stream)
{
  const float* x  = (const float*)d_in[0];
  const float* Wq = (const float*)d_in[1];
  const float* bq = (const float*)d_in[2];
  const float* Wk = (const float*)d_in[3];
  const float* bk = (const float*)d_in[4];
  float* out = (float*)d_out;

  char* w = (char*)d_ws;
  unsigned short* xbf  = (unsigned short*)w;  w += (size_t)B_ * T_ * E_ * 2;       // 16.8 MB
  unsigned short* xT   = (unsigned short*)w;  w += (size_t)B_ * T_ * E_ * 2;       // 16.8 MB
  unsigned short* WT   = (unsigned short*)w;  w += (size_t)2 * E_ * E_ * 2;        // 1 MB
  float*          bqk  = (float*)w;           w += (size_t)2 * E_ * 4;             // 4 KB
  unsigned short* qk   = (unsigned short*)w;  w += (size_t)B_ * T_ * 2 * E_ * 2;   // 33.6 MB
  unsigned short* attn = (unsigned short*)w;  w += (size_t)B_ * T_ * T_ * 2;       // 67 MB

  const float scale = 0.044194173824159216f;  // 512^-0.5

  conv_x_kernel<<<4096, 256, 0, stream>>>(x, xbf);
  conv_w_kernel<<<2048, 256, 0, stream>>>(Wq, Wk, bq, bk, WT, bqk, scale);
  trans_x_kernel<<<dim3(32, 8, 8), 256, 0, stream>>>(x, xT);

  // qk[M=16384, N=1024] = x_bf16 @ WT^T  (+bias, q-half pre-scaled)
  gemm_bt<1><<<dim3(8, 128, 1), 256, 0, stream>>>(
      xbf, E_, 0, WT, E_, 0, qk, 2 * E_, 0, E_, bqk);

  // scores[b][2048,2048] = q_b @ k_b^T   (q = cols 0..511 of qk, k = cols 512..1023)
  gemm_bt<1><<<dim3(16, 16, 8), 256, 0, stream>>>(
      qk, 2 * E_, (long long)T_ * 2 * E_,
      qk + E_, 2 * E_, (long long)T_ * 2 * E_,
      attn, T_, (long long)T_ * T_, E_, nullptr);

  softmax_kernel<<<4096, 256, 0, stream>>>(attn);

  // out[b][2048,512] = attn_b @ x_b  (B-operand = xT_b, N-major)
  gemm_bt<0><<<dim3(4, 16, 8), 256, 0, stream>>>(
      attn, T_, (long long)T_ * T_,
      xT, T_, (long long)E_ * T_,
      out, E_, (long long)T_ * E_, T_, nullptr);
}

// Round 3
// 177.487 us; speedup vs baseline: 1.1664x; 1.1664x over previous
//
#include <hip/hip_runtime.h>
#include <hip/hip_bf16.h>
#include <stdint.h>

#define B_  8
#define T_  2048
#define E_  512

typedef __attribute__((ext_vector_type(8))) __bf16 bf16x8;
typedef __attribute__((ext_vector_type(8))) unsigned short ushort8;
typedef __attribute__((ext_vector_type(4))) unsigned short ushort4v;
typedef __attribute__((ext_vector_type(4))) float f32x4;

__device__ __forceinline__ float bf2f(unsigned short u) {
  union { unsigned int u; float f; } c; c.u = ((unsigned int)u) << 16; return c.f;
}
__device__ __forceinline__ unsigned short f2bf(float f) {
  union { float f; unsigned int u; } c; c.f = f;
  unsigned int u = c.u;
  unsigned int r = (u + 0x7FFFu + ((u >> 16) & 1u)) >> 16;
  return (unsigned short)r;
}

__device__ __forceinline__ void gload_lds16(const void* g, void* l) {
  __builtin_amdgcn_global_load_lds(
      (const __attribute__((address_space(1))) uint32_t*)g,
      (__attribute__((address_space(3))) uint32_t*)l, 16, 0, 0);
}

// ---------------- fused bf16-convert + transpose ----------------
__global__ __launch_bounds__(256)
void trans_conv_kernel(const float* __restrict__ x, unsigned short* __restrict__ xbf,
                       unsigned short* __restrict__ xT) {
  __shared__ unsigned short tile[64][66];
  const int t0 = blockIdx.x * 64, e0 = blockIdx.y * 64, b = blockIdx.z;
  const int tid = threadIdx.x;
  const float* xb = x + ((size_t)b * T_ + t0) * E_ + e0;
  unsigned short* xbf_b = xbf + ((size_t)b * T_ + t0) * E_ + e0;
#pragma unroll
  for (int it = 0; it < 4; ++it) {
    int tr = (tid >> 4) + it * 16;
    int ec = (tid & 15) * 4;
    float4 f = *reinterpret_cast<const float4*>(xb + (size_t)tr * E_ + ec);
    ushort4v o;
    o[0] = f2bf(f.x); o[1] = f2bf(f.y); o[2] = f2bf(f.z); o[3] = f2bf(f.w);
    *reinterpret_cast<ushort4v*>(xbf_b + (size_t)tr * E_ + ec) = o;
    tile[ec + 0][tr] = o[0];
    tile[ec + 1][tr] = o[1];
    tile[ec + 2][tr] = o[2];
    tile[ec + 3][tr] = o[3];
  }
  __syncthreads();
  unsigned short* dst = xT + ((size_t)b * E_ + e0) * T_ + t0;
#pragma unroll
  for (int it = 0; it < 2; ++it) {
    int er = (tid >> 3) + it * 32;
    int tg = (tid & 7) * 8;
    ushort8 r;
#pragma unroll
    for (int j = 0; j < 8; ++j) r[j] = tile[er][tg + j];
    *reinterpret_cast<ushort8*>(dst + (size_t)er * T_ + tg) = r;
  }
}

// WT[n][kk] = (n<512 ? Wq[kk][n]*scale : Wk[kk][n-512]);  bqk[n] fused bias
__global__ __launch_bounds__(256)
void conv_w_kernel(const float* __restrict__ Wq, const float* __restrict__ Wk,
                   const float* __restrict__ bq, const float* __restrict__ bk,
                   unsigned short* __restrict__ WT, float* __restrict__ bqk, float scale) {
  int idx = blockIdx.x * 256 + threadIdx.x;
  int n  = idx >> 9;
  int kk = idx & 511;
  float v = (n < E_) ? Wq[kk * E_ + n] * scale : Wk[kk * E_ + (n - E_)];
  WT[idx] = f2bf(v);
  if (idx < 2 * E_) {
    float bv = (idx < E_) ? bq[idx] * scale : bk[idx - E_];
    bqk[idx] = bv;
  }
}

// ================= 256x256 8-phase GEMM (T1+T2+T3/T4+T5) =================
// C[M,N] = A[M,K] @ B'[N,K]^T, bf16 in, f32 acc. BK=64, 8 waves (2Mx4N),
// per-wave 128x64 output, 128 KiB LDS double-buffer, XOR-swizzled tiles.
// pp MUST be the buffer index 0/1 (element base = pp*32768).
#define READ_A(pp, ha) do {                                                    \
  const int rbase = (pp) * 32768 + aRow + (ha) * 4096;                         \
  _Pragma("unroll") for (int m = 0; m < 4; ++m) {                              \
    aA[m][0] = *reinterpret_cast<const bf16x8*>(&sm[rbase + m * 1024 + aCol0]);\
    aA[m][1] = *reinterpret_cast<const bf16x8*>(&sm[rbase + m * 1024 + aCol1]);\
  } } while (0)

#define READ_B(pp, hb) do {                                                    \
  const int rbase = (pp) * 32768 + bRow + (hb) * 2048;                         \
  _Pragma("unroll") for (int n = 0; n < 2; ++n) {                              \
    bB[hb][n][0] = *reinterpret_cast<const bf16x8*>(&sm[rbase + n * 1024 + aCol0]);\
    bB[hb][n][1] = *reinterpret_cast<const bf16x8*>(&sm[rbase + n * 1024 + aCol1]);\
  } } while (0)

#define MFMA_Q(ha, hb) do {                                                    \
  _Pragma("unroll") for (int m = 0; m < 4; ++m)                                \
  _Pragma("unroll") for (int n = 0; n < 2; ++n) {                              \
    acc[(ha)*4+m][(hb)*2+n] = __builtin_amdgcn_mfma_f32_16x16x32_bf16(         \
        aA[m][0], bB[hb][n][0], acc[(ha)*4+m][(hb)*2+n], 0, 0, 0);             \
    acc[(ha)*4+m][(hb)*2+n] = __builtin_amdgcn_mfma_f32_16x16x32_bf16(         \
        aA[m][1], bB[hb][n][1], acc[(ha)*4+m][(hb)*2+n], 0, 0, 0);             \
  } } while (0)

#define STAGE_OP(gptr, ld, base, kt) do {                                      \
  _Pragma("unroll") for (int h = 0; h < 2; ++h)                                \
  _Pragma("unroll") for (int rr2 = 0; rr2 < 2; ++rr2)                          \
    gload_lds16(gptr + (long long)(h * 128 + rr2 * 64) * (ld) + (long long)(kt) * 64, \
                &sm[(base) + h * 8192 + rr2 * 4096 + wv * 512]);               \
  } while (0)

template<int OUT_BF16>
__global__ __launch_bounds__(512)
void gemm256(const unsigned short* __restrict__ A, int lda, long long strA,
             const unsigned short* __restrict__ B, int ldb, long long strB,
             void* __restrict__ Cv, int ldc, long long strC,
             int K, const float* __restrict__ bias, int NBX, int NBY)
{
  __shared__ unsigned short sm[65536];   // 128 KiB: [2 bufs][A 32KB | B 32KB]
  const int tid  = threadIdx.x;
  const int lane = tid & 63;
  const int wv   = tid >> 6;
  const int wr   = wv >> 2;          // 0..1
  const int wc   = wv & 3;           // 0..3
  const int fr   = lane & 15;

  // bijective XCD-aware block swizzle (m204)
  const int nwg = gridDim.x, bid = blockIdx.x;
  const int qq = nwg >> 3, rr = nwg & 7, xc = bid & 7, ii = bid >> 3;
  const int wg = (xc < rr ? xc * (qq + 1) : rr * (qq + 1) + (xc - rr) * qq) + ii;
  const int bx = wg % NBX;
  const int tt = wg / NBX;
  const int by = tt % NBY;
  const int bz = tt / NBY;

  const long long m0 = (long long)by * 256;
  const long long n0 = (long long)bx * 256;
  const unsigned short* Ab = A + (long long)bz * strA + m0 * lda;
  const unsigned short* Bb = B + (long long)bz * strB + n0 * ldb;

  // staging: linear LDS dest, inverse-swizzled global source (rule #21)
  const int srow = tid >> 3;                                  // 0..63
  const int scol = ((tid & 7) * 8) ^ ((srow & 7) << 3);
  const unsigned short* gA = Ab + (long long)srow * lda + scol;
  const unsigned short* gB = Bb + (long long)srow * ldb + scol;

  // fragment-read addressing (swizzled): row&7 == fr&7 for all fragments
  const int xorc  = (fr & 7) << 3;
  const int q8    = (lane >> 4) * 8;
  const int aCol0 = (q8) ^ xorc;
  const int aCol1 = (32 + q8) ^ xorc;
  const int aRow  = (wr * 128 + fr) * 64;
  const int bRow  = 16384 + (wc * 64 + fr) * 64;

  f32x4 acc[8][4];
#pragma unroll
  for (int i = 0; i < 8; ++i)
#pragma unroll
    for (int j = 0; j < 4; ++j) acc[i][j] = (f32x4){0.f, 0.f, 0.f, 0.f};

  bf16x8 aA[4][2], bB[2][2][2];
  const int NT = K >> 6;

  STAGE_OP(gA, lda, 0, 0);
  STAGE_OP(gB, ldb, 16384, 0);
  asm volatile("s_waitcnt vmcnt(0)" ::: "memory");
  __builtin_amdgcn_s_barrier();

  int p = 0;
  for (int kt = 0; kt < NT; ++kt) {
    const int pn = p ^ 1;
    const int pnb = pn * 32768;
    // ---- phase 0: Q(0,0) ----
    READ_A(p, 0);
    READ_B(p, 0);
    if (kt + 1 < NT) STAGE_OP(gA, lda, pnb, kt + 1);
    __builtin_amdgcn_s_barrier();
    __builtin_amdgcn_s_setprio(1); MFMA_Q(0, 0); __builtin_amdgcn_s_setprio(0);
    __builtin_amdgcn_s_barrier();
    // ---- phase 1: Q(0,1) ----
    READ_B(p, 1);
    if (kt + 1 < NT) STAGE_OP(gB, ldb, pnb + 16384, kt + 1);
    __builtin_amdgcn_s_barrier();
    __builtin_amdgcn_s_setprio(1); MFMA_Q(0, 1); __builtin_amdgcn_s_setprio(0);
    __builtin_amdgcn_s_barrier();
    // ---- phase 2: Q(1,0) ----
    READ_A(p, 1);
    __builtin_amdgcn_s_barrier();
    __builtin_amdgcn_s_setprio(1); MFMA_Q(1, 0); __builtin_amdgcn_s_setprio(0);
    __builtin_amdgcn_s_barrier();
    // ---- phase 3: Q(1,1) ----
    __builtin_amdgcn_s_setprio(1); MFMA_Q(1, 1); __builtin_amdgcn_s_setprio(0);
    asm volatile("s_waitcnt vmcnt(0)" ::: "memory");
    __builtin_amdgcn_s_barrier();
    p = pn;
  }

  // ---- epilogue ----
  const int rq = (lane >> 4) * 4;
  if (bias) {
#pragma unroll
    for (int nn = 0; nn < 4; ++nn) {
      const float bv = bias[n0 + wc * 64 + (nn >> 1) * 32 + (nn & 1) * 16 + fr];
#pragma unroll
      for (int mm = 0; mm < 8; ++mm)
#pragma unroll
        for (int j = 0; j < 4; ++j) acc[mm][nn][j] += bv;
    }
  }
  if (OUT_BF16) {
    unsigned short* C = (unsigned short*)Cv + (long long)bz * strC;
#pragma unroll
    for (int mm = 0; mm < 8; ++mm)
#pragma unroll
      for (int j = 0; j < 4; ++j) {
        const long long row = m0 + wr * 128 + (mm >> 2) * 64 + (mm & 3) * 16 + rq + j;
#pragma unroll
        for (int nn = 0; nn < 4; ++nn) {
          const long long col = n0 + wc * 64 + (nn >> 1) * 32 + (nn & 1) * 16 + fr;
          C[row * ldc + col] = f2bf(acc[mm][nn][j]);
        }
      }
  } else {
    float* C = (float*)Cv + (long long)bz * strC;
#pragma unroll
    for (int mm = 0; mm < 8; ++mm)
#pragma unroll
      for (int j = 0; j < 4; ++j) {
        const long long row = m0 + wr * 128 + (mm >> 2) * 64 + (mm & 3) * 16 + rq + j;
#pragma unroll
        for (int nn = 0; nn < 4; ++nn) {
          const long long col = n0 + wc * 64 + (nn >> 1) * 32 + (nn & 1) * 16 + fr;
          C[row * ldc + col] = acc[mm][nn][j];
        }
      }
  }
}

// ---------------- m97-style 128x128 GEMM (kept for PV) ----------------
template<int OUT_BF16>
__global__ __launch_bounds__(256)
void gemm_bt(const unsigned short* __restrict__ A, int lda, long long strA,
             const unsigned short* __restrict__ B, int ldb, long long strB,
             void* __restrict__ Cv, int ldc, long long strC,
             int K, const float* __restrict__ bias)
{
  __shared__ unsigned short sA[128 * 32];
  __shared__ unsigned short sB[128 * 32];
  const int tid  = threadIdx.x;
  const int lane = tid & 63;
  const int wv   = tid >> 6;
  const int wr   = wv >> 1;
  const int wc   = wv & 1;
  const long long m0 = (long long)blockIdx.y * 128;
  const long long n0 = (long long)blockIdx.x * 128;
  const unsigned short* Ab = A + (long long)blockIdx.z * strA + m0 * lda;
  const unsigned short* Bb = B + (long long)blockIdx.z * strB + n0 * ldb;

  f32x4 acc[4][4];
#pragma unroll
  for (int i = 0; i < 4; ++i)
#pragma unroll
    for (int j = 0; j < 4; ++j) acc[i][j] = (f32x4){0.f, 0.f, 0.f, 0.f};

  const int srow = lane >> 2;
  const int ke   = (lane & 3) * 8;
  const int fr   = lane & 15;
  const int fo   = (lane >> 4) * 8;

  const int nsteps = K >> 5;
  for (int kt = 0; kt < nsteps; ++kt) {
    const int kbase = kt * 32;
#pragma unroll
    for (int it = 0; it < 2; ++it) {
      const int c   = it * 4 + wv;
      const int row = c * 16 + srow;
      gload_lds16(Ab + (long long)row * lda + kbase + ke, &sA[c * 512]);
      gload_lds16(Bb + (long long)row * ldb + kbase + ke, &sB[c * 512]);
    }
    __syncthreads();
    bf16x8 af[4], bfv[4];
#pragma unroll
    for (int m = 0; m < 4; ++m)
      af[m] = *reinterpret_cast<const bf16x8*>(&sA[(wr * 64 + m * 16 + fr) * 32 + fo]);
#pragma unroll
    for (int n = 0; n < 4; ++n)
      bfv[n] = *reinterpret_cast<const bf16x8*>(&sB[(wc * 64 + n * 16 + fr) * 32 + fo]);
#pragma unroll
    for (int m = 0; m < 4; ++m)
#pragma unroll
      for (int n = 0; n < 4; ++n)
        acc[m][n] = __builtin_amdgcn_mfma_f32_16x16x32_bf16(af[m], bfv[n], acc[m][n], 0, 0, 0);
    __syncthreads();
  }

  const int rq = (lane >> 4) * 4;
  if (OUT_BF16) {
    unsigned short* C = (unsigned short*)Cv + (long long)blockIdx.z * strC;
#pragma unroll
    for (int m = 0; m < 4; ++m)
#pragma unroll
      for (int j = 0; j < 4; ++j) {
        const long long row = m0 + wr * 64 + m * 16 + rq + j;
#pragma unroll
        for (int n = 0; n < 4; ++n) {
          const long long col = n0 + wc * 64 + n * 16 + fr;
          C[row * ldc + col] = f2bf(acc[m][n][j]);
        }
      }
  } else {
    float* C = (float*)Cv + (long long)blockIdx.z * strC;
#pragma unroll
    for (int m = 0; m < 4; ++m)
#pragma unroll
      for (int j = 0; j < 4; ++j) {
        const long long row = m0 + wr * 64 + m * 16 + rq + j;
#pragma unroll
        for (int n = 0; n < 4; ++n) {
          const long long col = n0 + wc * 64 + n * 16 + fr;
          C[row * ldc + col] = acc[m][n][j];
        }
      }
  }
}

// ---------------- row softmax over 2048 cols, one wave per row ----------------
__global__ __launch_bounds__(256)
void softmax_kernel(unsigned short* __restrict__ attn) {
  const int row  = blockIdx.x * 4 + (threadIdx.x >> 6);
  const int lane = threadIdx.x & 63;
  unsigned short* p = attn + (size_t)row * T_;

  float v[32];
#pragma unroll
  for (int c = 0; c < 4; ++c) {
    ushort8 s = *reinterpret_cast<const ushort8*>(p + c * 512 + lane * 8);
#pragma unroll
    for (int j = 0; j < 8; ++j) v[c * 8 + j] = bf2f(s[j]);
  }
  float mx = v[0];
#pragma unroll
  for (int i = 1; i < 32; ++i) mx = fmaxf(mx, v[i]);
#pragma unroll
  for (int o = 32; o > 0; o >>= 1) mx = fmaxf(mx, __shfl_xor(mx, o));

  float sum = 0.f;
#pragma unroll
  for (int i = 0; i < 32; ++i) { v[i] = __expf(v[i] - mx); sum += v[i]; }
#pragma unroll
  for (int o = 32; o > 0; o >>= 1) sum += __shfl_xor(sum, o);
  const float inv = 1.0f / sum;

#pragma unroll
  for (int c = 0; c < 4; ++c) {
    ushort8 r;
#pragma unroll
    for (int j = 0; j < 8; ++j) r[j] = f2bf(v[c * 8 + j] * inv);
    *reinterpret_cast<ushort8*>(p + c * 512 + lane * 8) = r;
  }
}

// ---------------- launch ----------------
extern "C" void kernel_launch(void* const* d_in, const int* in_sizes, int n_in,
                              void* d_out, int out_size, void* d_ws, size_t ws_size,
                              hipStream_t stream)
{
  const float* x  = (const float*)d_in[0];
  const float* Wq = (const float*)d_in[1];
  const float* bq = (const float*)d_in[2];
  const float* Wk = (const float*)d_in[3];
  const float* bk = (const float*)d_in[4];
  float* out = (float*)d_out;

  char* w = (char*)d_ws;
  unsigned short* xbf  = (unsigned short*)w;  w += (size_t)B_ * T_ * E_ * 2;
  unsigned short* xT   = (unsigned short*)w;  w += (size_t)B_ * T_ * E_ * 2;
  unsigned short* WT   = (unsigned short*)w;  w += (size_t)2 * E_ * E_ * 2;
  float*          bqk  = (float*)w;           w += (size_t)2 * E_ * 4;
  unsigned short* qk   = (unsigned short*)w;  w += (size_t)B_ * T_ * 2 * E_ * 2;
  unsigned short* attn = (unsigned short*)w;  w += (size_t)B_ * T_ * T_ * 2;

  const float scale = 0.044194173824159216f;  // 512^-0.5

  trans_conv_kernel<<<dim3(32, 8, 8), 256, 0, stream>>>(x, xbf, xT);
  conv_w_kernel<<<2048, 256, 0, stream>>>(Wq, Wk, bq, bk, WT, bqk, scale);

  // qk[16384, 1024] = xbf @ WT^T (+fused bias/scale)   grid 64x4 = 256 blocks
  gemm256<1><<<256, 512, 0, stream>>>(
      xbf, E_, 0, WT, E_, 0, qk, 2 * E_, 0, E_, bqk, 4, 64);

  // scores[b][2048,2048] = q_b @ k_b^T                 grid 8x8x8 = 512 blocks
  gemm256<1><<<512, 512, 0, stream>>>(
      qk, 2 * E_, (long long)T_ * 2 * E_,
      qk + E_, 2 * E_, (long long)T_ * 2 * E_,
      attn, T_, (long long)T_ * T_, E_, nullptr, 8, 8);

  softmax_kernel<<<4096, 256, 0, stream>>>(attn);

  // out[b][2048,512] = attn_b @ x_b
  gemm_bt<0><<<dim3(4, 16, 8), 256, 0, stream>>>(
      attn, T_, (long long)T_ * T_,
      xT, T_, (long long)E_ * T_,
      out, E_, (long long)T_ * E_, T_, nullptr);
}

// Round 4
// 140.675 us; speedup vs baseline: 1.4716x; 1.2617x over previous
//
#include <hip/hip_runtime.h>
#include <hip/hip_bf16.h>
#include <stdint.h>

#define B_  8
#define T_  2048
#define E_  512

typedef __attribute__((ext_vector_type(8))) __bf16 bf16x8;
typedef __attribute__((ext_vector_type(8))) unsigned short ushort8;
typedef __attribute__((ext_vector_type(4))) unsigned short ushort4v;
typedef __attribute__((ext_vector_type(4))) float f32x4;

__device__ __forceinline__ float bf2f(unsigned short u) {
  union { unsigned int u; float f; } c; c.u = ((unsigned int)u) << 16; return c.f;
}
__device__ __forceinline__ unsigned short f2bf(float f) {
  union { float f; unsigned int u; } c; c.f = f;
  unsigned int u = c.u;
  unsigned int r = (u + 0x7FFFu + ((u >> 16) & 1u)) >> 16;
  return (unsigned short)r;
}

__device__ __forceinline__ void gload_lds16(const void* g, void* l) {
  __builtin_amdgcn_global_load_lds(
      (const __attribute__((address_space(1))) uint32_t*)g,
      (__attribute__((address_space(3))) uint32_t*)l, 16, 0, 0);
}

__device__ __forceinline__ float sum8(bf16x8 v) {
  float s = 0.f;
#pragma unroll
  for (int j = 0; j < 8; ++j) s += (float)v[j];
  return s;
}

// ---------------- fused bf16-convert + transpose ----------------
__global__ __launch_bounds__(256)
void trans_conv_kernel(const float* __restrict__ x, unsigned short* __restrict__ xbf,
                       unsigned short* __restrict__ xT) {
  __shared__ unsigned short tile[64][66];
  const int t0 = blockIdx.x * 64, e0 = blockIdx.y * 64, b = blockIdx.z;
  const int tid = threadIdx.x;
  const float* xb = x + ((size_t)b * T_ + t0) * E_ + e0;
  unsigned short* xbf_b = xbf + ((size_t)b * T_ + t0) * E_ + e0;
#pragma unroll
  for (int it = 0; it < 4; ++it) {
    int tr = (tid >> 4) + it * 16;
    int ec = (tid & 15) * 4;
    float4 f = *reinterpret_cast<const float4*>(xb + (size_t)tr * E_ + ec);
    ushort4v o;
    o[0] = f2bf(f.x); o[1] = f2bf(f.y); o[2] = f2bf(f.z); o[3] = f2bf(f.w);
    *reinterpret_cast<ushort4v*>(xbf_b + (size_t)tr * E_ + ec) = o;
    tile[ec + 0][tr] = o[0];
    tile[ec + 1][tr] = o[1];
    tile[ec + 2][tr] = o[2];
    tile[ec + 3][tr] = o[3];
  }
  __syncthreads();
  unsigned short* dst = xT + ((size_t)b * E_ + e0) * T_ + t0;
#pragma unroll
  for (int it = 0; it < 2; ++it) {
    int er = (tid >> 3) + it * 32;
    int tg = (tid & 7) * 8;
    ushort8 r;
#pragma unroll
    for (int j = 0; j < 8; ++j) r[j] = tile[er][tg + j];
    *reinterpret_cast<ushort8*>(dst + (size_t)er * T_ + tg) = r;
  }
}

// WT[n][kk] = (n<512 ? Wq[kk][n]*scale : Wk[kk][n-512]);  bqk[n] fused bias
__global__ __launch_bounds__(256)
void conv_w_kernel(const float* __restrict__ Wq, const float* __restrict__ Wk,
                   const float* __restrict__ bq, const float* __restrict__ bk,
                   unsigned short* __restrict__ WT, float* __restrict__ bqk, float scale) {
  int idx = blockIdx.x * 256 + threadIdx.x;
  int n  = idx >> 9;
  int kk = idx & 511;
  float v = (n < E_) ? Wq[kk * E_ + n] * scale : Wk[kk * E_ + (n - E_)];
  WT[idx] = f2bf(v);
  if (idx < 2 * E_) {
    float bv = (idx < E_) ? bq[idx] * scale : bk[idx - E_];
    bqk[idx] = bv;
  }
}

// ================= 256x256 8-phase GEMM =================
#define READ_A(pp, ha) do {                                                    \
  const int rbase = (pp) * 32768 + aRow + (ha) * 4096;                         \
  _Pragma("unroll") for (int m = 0; m < 4; ++m) {                              \
    aA[m][0] = *reinterpret_cast<const bf16x8*>(&sm[rbase + m * 1024 + aCol0]);\
    aA[m][1] = *reinterpret_cast<const bf16x8*>(&sm[rbase + m * 1024 + aCol1]);\
  } } while (0)

#define READ_B(pp, hb) do {                                                    \
  const int rbase = (pp) * 32768 + bRow + (hb) * 2048;                         \
  _Pragma("unroll") for (int n = 0; n < 2; ++n) {                              \
    bB[hb][n][0] = *reinterpret_cast<const bf16x8*>(&sm[rbase + n * 1024 + aCol0]);\
    bB[hb][n][1] = *reinterpret_cast<const bf16x8*>(&sm[rbase + n * 1024 + aCol1]);\
  } } while (0)

#define MFMA_Q(ha, hb) do {                                                    \
  _Pragma("unroll") for (int m = 0; m < 4; ++m)                                \
  _Pragma("unroll") for (int n = 0; n < 2; ++n) {                              \
    acc[(ha)*4+m][(hb)*2+n] = __builtin_amdgcn_mfma_f32_16x16x32_bf16(         \
        aA[m][0], bB[hb][n][0], acc[(ha)*4+m][(hb)*2+n], 0, 0, 0);             \
    acc[(ha)*4+m][(hb)*2+n] = __builtin_amdgcn_mfma_f32_16x16x32_bf16(         \
        aA[m][1], bB[hb][n][1], acc[(ha)*4+m][(hb)*2+n], 0, 0, 0);             \
  } } while (0)

#define STAGE_OP(gptr, ld, base, kt) do {                                      \
  _Pragma("unroll") for (int h = 0; h < 2; ++h)                                \
  _Pragma("unroll") for (int rr2 = 0; rr2 < 2; ++rr2)                          \
    gload_lds16(gptr + (long long)(h * 128 + rr2 * 64) * (ld) + (long long)(kt) * 64, \
                &sm[(base) + h * 8192 + rr2 * 4096 + wv * 512]);               \
  } while (0)

template<int OUT_BF16, int DO_EXP>
__global__ __launch_bounds__(512)
void gemm256(const unsigned short* __restrict__ A, int lda, long long strA,
             const unsigned short* __restrict__ B, int ldb, long long strB,
             void* __restrict__ Cv, int ldc, long long strC,
             int K, const float* __restrict__ bias, int NBX, int NBY)
{
  __shared__ unsigned short sm[65536];
  const int tid  = threadIdx.x;
  const int lane = tid & 63;
  const int wv   = tid >> 6;
  const int wr   = wv >> 2;
  const int wc   = wv & 3;
  const int fr   = lane & 15;

  const int nwg = gridDim.x, bid = blockIdx.x;
  const int qq = nwg >> 3, rr = nwg & 7, xc = bid & 7, ii = bid >> 3;
  const int wg = (xc < rr ? xc * (qq + 1) : rr * (qq + 1) + (xc - rr) * qq) + ii;
  const int bx = wg % NBX;
  const int tt = wg / NBX;
  const int by = tt % NBY;
  const int bz = tt / NBY;

  const long long m0 = (long long)by * 256;
  const long long n0 = (long long)bx * 256;
  const unsigned short* Ab = A + (long long)bz * strA + m0 * lda;
  const unsigned short* Bb = B + (long long)bz * strB + n0 * ldb;

  const int srow = tid >> 3;
  const int scol = ((tid & 7) * 8) ^ ((srow & 7) << 3);
  const unsigned short* gA = Ab + (long long)srow * lda + scol;
  const unsigned short* gB = Bb + (long long)srow * ldb + scol;

  const int xorc  = (fr & 7) << 3;
  const int q8    = (lane >> 4) * 8;
  const int aCol0 = (q8) ^ xorc;
  const int aCol1 = (32 + q8) ^ xorc;
  const int aRow  = (wr * 128 + fr) * 64;
  const int bRow  = 16384 + (wc * 64 + fr) * 64;

  f32x4 acc[8][4];
#pragma unroll
  for (int i = 0; i < 8; ++i)
#pragma unroll
    for (int j = 0; j < 4; ++j) acc[i][j] = (f32x4){0.f, 0.f, 0.f, 0.f};

  bf16x8 aA[4][2], bB[2][2][2];
  const int NT = K >> 6;

  STAGE_OP(gA, lda, 0, 0);
  STAGE_OP(gB, ldb, 16384, 0);
  asm volatile("s_waitcnt vmcnt(0)" ::: "memory");
  __builtin_amdgcn_s_barrier();

  int p = 0;
  for (int kt = 0; kt < NT; ++kt) {
    const int pn = p ^ 1;
    const int pnb = pn * 32768;
    READ_A(p, 0);
    READ_B(p, 0);
    if (kt + 1 < NT) STAGE_OP(gA, lda, pnb, kt + 1);
    __builtin_amdgcn_s_barrier();
    __builtin_amdgcn_s_setprio(1); MFMA_Q(0, 0); __builtin_amdgcn_s_setprio(0);
    __builtin_amdgcn_s_barrier();
    READ_B(p, 1);
    if (kt + 1 < NT) STAGE_OP(gB, ldb, pnb + 16384, kt + 1);
    __builtin_amdgcn_s_barrier();
    __builtin_amdgcn_s_setprio(1); MFMA_Q(0, 1); __builtin_amdgcn_s_setprio(0);
    __builtin_amdgcn_s_barrier();
    READ_A(p, 1);
    __builtin_amdgcn_s_barrier();
    __builtin_amdgcn_s_setprio(1); MFMA_Q(1, 0); __builtin_amdgcn_s_setprio(0);
    __builtin_amdgcn_s_barrier();
    __builtin_amdgcn_s_setprio(1); MFMA_Q(1, 1); __builtin_amdgcn_s_setprio(0);
    asm volatile("s_waitcnt vmcnt(0)" ::: "memory");
    __builtin_amdgcn_s_barrier();
    p = pn;
  }

  const int rq = (lane >> 4) * 4;
  if (bias) {
#pragma unroll
    for (int nn = 0; nn < 4; ++nn) {
      const float bv = bias[n0 + wc * 64 + (nn >> 1) * 32 + (nn & 1) * 16 + fr];
#pragma unroll
      for (int mm = 0; mm < 8; ++mm)
#pragma unroll
        for (int j = 0; j < 4; ++j) acc[mm][nn][j] += bv;
    }
  }
  if (DO_EXP) {
#pragma unroll
    for (int mm = 0; mm < 8; ++mm)
#pragma unroll
      for (int nn = 0; nn < 4; ++nn)
#pragma unroll
        for (int j = 0; j < 4; ++j) acc[mm][nn][j] = __expf(acc[mm][nn][j]);
  }
  if (OUT_BF16) {
    unsigned short* C = (unsigned short*)Cv + (long long)bz * strC;
#pragma unroll
    for (int mm = 0; mm < 8; ++mm)
#pragma unroll
      for (int j = 0; j < 4; ++j) {
        const long long row = m0 + wr * 128 + (mm >> 2) * 64 + (mm & 3) * 16 + rq + j;
#pragma unroll
        for (int nn = 0; nn < 4; ++nn) {
          const long long col = n0 + wc * 64 + (nn >> 1) * 32 + (nn & 1) * 16 + fr;
          C[row * ldc + col] = f2bf(acc[mm][nn][j]);
        }
      }
  } else {
    float* C = (float*)Cv + (long long)bz * strC;
#pragma unroll
    for (int mm = 0; mm < 8; ++mm)
#pragma unroll
      for (int j = 0; j < 4; ++j) {
        const long long row = m0 + wr * 128 + (mm >> 2) * 64 + (mm & 3) * 16 + rq + j;
#pragma unroll
        for (int nn = 0; nn < 4; ++nn) {
          const long long col = n0 + wc * 64 + (nn >> 1) * 32 + (nn & 1) * 16 + fr;
          C[row * ldc + col] = acc[mm][nn][j];
        }
      }
  }
}

// ================= PV GEMM: out = P @ V, fused rowsum + divide =================
// BM=256, BN=128, BK=64, 8 waves (4M x 2N), per-wave 64x64. A = P (exp'd, bf16),
// B = xT (N-major). Each block spans full K -> computes rowsum deterministically.
__global__ __launch_bounds__(512)
void gemm_pv(const unsigned short* __restrict__ A, int lda, long long strA,
             const unsigned short* __restrict__ B, int ldb, long long strB,
             float* __restrict__ C, int ldc, long long strC, int K)
{
  __shared__ unsigned short sm[49152];   // 96 KiB: 2 bufs x (A 32KB + B 16KB)
  const int tid  = threadIdx.x;
  const int lane = tid & 63;
  const int wv   = tid >> 6;
  const int wr   = wv >> 1;          // 0..3
  const int wc   = wv & 1;           // 0..1
  const int fr   = lane & 15;

  // bijective XCD swizzle; grid = 256 -> batch == XCD (xT L2-resident)
  const int nwg = gridDim.x, bid = blockIdx.x;
  const int qq = nwg >> 3, rr = nwg & 7, xc = bid & 7, ii = bid >> 3;
  const int wg = (xc < rr ? xc * (qq + 1) : rr * (qq + 1) + (xc - rr) * qq) + ii;
  const int bx = wg & 3;             // N: 512/128
  const int by = (wg >> 2) & 7;      // M: 2048/256
  const int bz = wg >> 5;            // batch

  const long long m0 = (long long)by * 256;
  const long long n0 = (long long)bx * 128;
  const unsigned short* Ab = A + (long long)bz * strA + m0 * lda;
  const unsigned short* Bb = B + (long long)bz * strB + n0 * ldb;

  const int srow = tid >> 3;
  const int scol = ((tid & 7) * 8) ^ ((srow & 7) << 3);
  const unsigned short* gA = Ab + (long long)srow * lda + scol;
  const unsigned short* gB = Bb + (long long)srow * ldb + scol;

  const int xorc  = (fr & 7) << 3;
  const int q8    = (lane >> 4) * 8;
  const int aCol0 = q8 ^ xorc;
  const int aCol1 = (32 + q8) ^ xorc;
  const int aRow  = (wr * 64 + fr) * 64;
  const int bRow  = 16384 + (wc * 64 + fr) * 64;

  f32x4 acc[4][4];
#pragma unroll
  for (int i = 0; i < 4; ++i)
#pragma unroll
    for (int j = 0; j < 4; ++j) acc[i][j] = (f32x4){0.f, 0.f, 0.f, 0.f};
  float rs0 = 0.f, rs1 = 0.f;
  bf16x8 aA[4][2], bB2[2][2];
  const int NT = K >> 6;

  // prologue: stage tile 0 into buffer 0 (A: 4 rounds, B: 2 rounds)
#pragma unroll
  for (int r = 0; r < 4; ++r)
    gload_lds16(gA + (long long)(r * 64) * lda, &sm[r * 4096 + wv * 512]);
#pragma unroll
  for (int r = 0; r < 2; ++r)
    gload_lds16(gB + (long long)(r * 64) * ldb, &sm[16384 + r * 4096 + wv * 512]);
  asm volatile("s_waitcnt vmcnt(0)" ::: "memory");
  __builtin_amdgcn_s_barrier();

  int p = 0;
  for (int kt = 0; kt < NT; ++kt) {
    const int pb = p * 24576, pnb = (p ^ 1) * 24576;
    const long long koff = (long long)(kt + 1) * 64;
    // ---- phase 0: n-half 0 ----
#pragma unroll
    for (int m = 0; m < 4; ++m) {
      aA[m][0] = *reinterpret_cast<const bf16x8*>(&sm[pb + aRow + m * 1024 + aCol0]);
      aA[m][1] = *reinterpret_cast<const bf16x8*>(&sm[pb + aRow + m * 1024 + aCol1]);
    }
#pragma unroll
    for (int n = 0; n < 2; ++n) {
      bB2[n][0] = *reinterpret_cast<const bf16x8*>(&sm[pb + bRow + n * 1024 + aCol0]);
      bB2[n][1] = *reinterpret_cast<const bf16x8*>(&sm[pb + bRow + n * 1024 + aCol1]);
    }
    if (kt + 1 < NT) {
      gload_lds16(gA + koff,                            &sm[pnb + 0     + wv * 512]);
      gload_lds16(gA + (long long)64  * lda + koff,     &sm[pnb + 4096  + wv * 512]);
      gload_lds16(gB + koff,                            &sm[pnb + 16384 + wv * 512]);
    }
    __builtin_amdgcn_s_barrier();
    __builtin_amdgcn_s_setprio(1);
#pragma unroll
    for (int m = 0; m < 4; ++m)
#pragma unroll
      for (int n = 0; n < 2; ++n) {
        acc[m][n] = __builtin_amdgcn_mfma_f32_16x16x32_bf16(aA[m][0], bB2[n][0], acc[m][n], 0, 0, 0);
        acc[m][n] = __builtin_amdgcn_mfma_f32_16x16x32_bf16(aA[m][1], bB2[n][1], acc[m][n], 0, 0, 0);
      }
    __builtin_amdgcn_s_setprio(0);
    // rowsum: wave sums its 2 statically-assigned m-frags (wave-uniform branch)
    if (wc == 0) { rs0 += sum8(aA[0][0]) + sum8(aA[0][1]); rs1 += sum8(aA[2][0]) + sum8(aA[2][1]); }
    else         { rs0 += sum8(aA[1][0]) + sum8(aA[1][1]); rs1 += sum8(aA[3][0]) + sum8(aA[3][1]); }
    __builtin_amdgcn_s_barrier();
    // ---- phase 1: n-half 1 ----
#pragma unroll
    for (int n = 0; n < 2; ++n) {
      bB2[n][0] = *reinterpret_cast<const bf16x8*>(&sm[pb + bRow + (2 + n) * 1024 + aCol0]);
      bB2[n][1] = *reinterpret_cast<const bf16x8*>(&sm[pb + bRow + (2 + n) * 1024 + aCol1]);
    }
    if (kt + 1 < NT) {
      gload_lds16(gA + (long long)128 * lda + koff,     &sm[pnb + 8192        + wv * 512]);
      gload_lds16(gA + (long long)192 * lda + koff,     &sm[pnb + 12288       + wv * 512]);
      gload_lds16(gB + (long long)64  * ldb + koff,     &sm[pnb + 16384 + 4096 + wv * 512]);
    }
    __builtin_amdgcn_s_barrier();
    __builtin_amdgcn_s_setprio(1);
#pragma unroll
    for (int m = 0; m < 4; ++m)
#pragma unroll
      for (int n = 0; n < 2; ++n) {
        acc[m][2 + n] = __builtin_amdgcn_mfma_f32_16x16x32_bf16(aA[m][0], bB2[n][0], acc[m][2 + n], 0, 0, 0);
        acc[m][2 + n] = __builtin_amdgcn_mfma_f32_16x16x32_bf16(aA[m][1], bB2[n][1], acc[m][2 + n], 0, 0, 0);
      }
    __builtin_amdgcn_s_setprio(0);
    asm volatile("s_waitcnt vmcnt(0)" ::: "memory");
    __builtin_amdgcn_s_barrier();
    p ^= 1;
  }

  // rowsum: reduce across the 4 k-lane-groups, share via LDS
  rs0 += __shfl_xor(rs0, 16); rs0 += __shfl_xor(rs0, 32);
  rs1 += __shfl_xor(rs1, 16); rs1 += __shfl_xor(rs1, 32);
  float* rsl = (float*)sm;
  if (lane < 16) {
    rsl[wr * 64 + wc * 16 + lane]      = rs0;   // rows of frag m = wc
    rsl[wr * 64 + 32 + wc * 16 + lane] = rs1;   // rows of frag m = 2+wc
  }
  __syncthreads();

  const int rq = (lane >> 4) * 4;
  float* Cb = C + (long long)bz * strC;
#pragma unroll
  for (int m = 0; m < 4; ++m)
#pragma unroll
    for (int j = 0; j < 4; ++j) {
      const int lrow = wr * 64 + m * 16 + rq + j;
      const float inv = 1.0f / rsl[lrow];
      const long long row = m0 + lrow;
#pragma unroll
      for (int n = 0; n < 4; ++n)
        Cb[row * ldc + n0 + wc * 64 + n * 16 + fr] = acc[m][n][j] * inv;
    }
}

// ---------------- launch ----------------
extern "C" void kernel_launch(void* const* d_in, const int* in_sizes, int n_in,
                              void* d_out, int out_size, void* d_ws, size_t ws_size,
                              hipStream_t stream)
{
  const float* x  = (const float*)d_in[0];
  const float* Wq = (const float*)d_in[1];
  const float* bq = (const float*)d_in[2];
  const float* Wk = (const float*)d_in[3];
  const float* bk = (const float*)d_in[4];
  float* out = (float*)d_out;

  char* w = (char*)d_ws;
  unsigned short* xbf  = (unsigned short*)w;  w += (size_t)B_ * T_ * E_ * 2;
  unsigned short* xT   = (unsigned short*)w;  w += (size_t)B_ * T_ * E_ * 2;
  unsigned short* WT   = (unsigned short*)w;  w += (size_t)2 * E_ * E_ * 2;
  float*          bqk  = (float*)w;           w += (size_t)2 * E_ * 4;
  unsigned short* qk   = (unsigned short*)w;  w += (size_t)B_ * T_ * 2 * E_ * 2;
  unsigned short* attn = (unsigned short*)w;  w += (size_t)B_ * T_ * T_ * 2;

  const float scale = 0.044194173824159216f;  // 512^-0.5

  trans_conv_kernel<<<dim3(32, 8, 8), 256, 0, stream>>>(x, xbf, xT);
  conv_w_kernel<<<2048, 256, 0, stream>>>(Wq, Wk, bq, bk, WT, bqk, scale);

  // qk[16384, 1024] = xbf @ WT^T (+fused bias/scale)
  gemm256<1, 0><<<256, 512, 0, stream>>>(
      xbf, E_, 0, WT, E_, 0, qk, 2 * E_, 0, E_, bqk, 4, 64);

  // P[b][2048,2048] = exp(q_b @ k_b^T)   (unnormalized, no-max softmax)
  gemm256<1, 1><<<512, 512, 0, stream>>>(
      qk, 2 * E_, (long long)T_ * 2 * E_,
      qk + E_, 2 * E_, (long long)T_ * 2 * E_,
      attn, T_, (long long)T_ * T_, E_, nullptr, 8, 8);

  // out[b][2048,512] = (P_b @ x_b) / rowsum(P_b)
  gemm_pv<<<256, 512, 0, stream>>>(
      attn, T_, (long long)T_ * T_,
      xT, T_, (long long)E_ * T_,
      out, E_, (long long)T_ * E_, T_);
}

// Round 5
// 139.503 us; speedup vs baseline: 1.4840x; 1.0084x over previous
//
#include <hip/hip_runtime.h>
#include <hip/hip_bf16.h>
#include <stdint.h>

#define B_  8
#define T_  2048
#define E_  512

typedef __attribute__((ext_vector_type(8))) __bf16 bf16x8;
typedef __attribute__((ext_vector_type(8))) unsigned short ushort8;
typedef __attribute__((ext_vector_type(4))) unsigned short ushort4v;
typedef __attribute__((ext_vector_type(4))) float f32x4;

__device__ __forceinline__ float bf2f(unsigned short u) {
  union { unsigned int u; float f; } c; c.u = ((unsigned int)u) << 16; return c.f;
}
__device__ __forceinline__ unsigned short f2bf(float f) {
  union { float f; unsigned int u; } c; c.f = f;
  unsigned int u = c.u;
  unsigned int r = (u + 0x7FFFu + ((u >> 16) & 1u)) >> 16;
  return (unsigned short)r;
}

__device__ __forceinline__ void gload_lds16(const void* g, void* l) {
  __builtin_amdgcn_global_load_lds(
      (const __attribute__((address_space(1))) uint32_t*)g,
      (__attribute__((address_space(3))) uint32_t*)l, 16, 0, 0);
}

// ---------------- fused bf16-convert + transpose ----------------
__global__ __launch_bounds__(256)
void trans_conv_kernel(const float* __restrict__ x, unsigned short* __restrict__ xbf,
                       unsigned short* __restrict__ xT) {
  __shared__ unsigned short tile[64][66];
  const int t0 = blockIdx.x * 64, e0 = blockIdx.y * 64, b = blockIdx.z;
  const int tid = threadIdx.x;
  const float* xb = x + ((size_t)b * T_ + t0) * E_ + e0;
  unsigned short* xbf_b = xbf + ((size_t)b * T_ + t0) * E_ + e0;
#pragma unroll
  for (int it = 0; it < 4; ++it) {
    int tr = (tid >> 4) + it * 16;
    int ec = (tid & 15) * 4;
    float4 f = *reinterpret_cast<const float4*>(xb + (size_t)tr * E_ + ec);
    ushort4v o;
    o[0] = f2bf(f.x); o[1] = f2bf(f.y); o[2] = f2bf(f.z); o[3] = f2bf(f.w);
    *reinterpret_cast<ushort4v*>(xbf_b + (size_t)tr * E_ + ec) = o;
    tile[ec + 0][tr] = o[0];
    tile[ec + 1][tr] = o[1];
    tile[ec + 2][tr] = o[2];
    tile[ec + 3][tr] = o[3];
  }
  __syncthreads();
  unsigned short* dst = xT + ((size_t)b * E_ + e0) * T_ + t0;
#pragma unroll
  for (int it = 0; it < 2; ++it) {
    int er = (tid >> 3) + it * 32;
    int tg = (tid & 7) * 8;
    ushort8 r;
#pragma unroll
    for (int j = 0; j < 8; ++j) r[j] = tile[er][tg + j];
    *reinterpret_cast<ushort8*>(dst + (size_t)er * T_ + tg) = r;
  }
}

// WT[n][kk] = (n<512 ? Wq[kk][n]*scale : Wk[kk][n-512]);  bqk[n] fused bias
__global__ __launch_bounds__(256)
void conv_w_kernel(const float* __restrict__ Wq, const float* __restrict__ Wk,
                   const float* __restrict__ bq, const float* __restrict__ bk,
                   unsigned short* __restrict__ WT, float* __restrict__ bqk, float scale) {
  int idx = blockIdx.x * 256 + threadIdx.x;
  int n  = idx >> 9;
  int kk = idx & 511;
  float v = (n < E_) ? Wq[kk * E_ + n] * scale : Wk[kk * E_ + (n - E_)];
  WT[idx] = f2bf(v);
  if (idx < 2 * E_) {
    float bv = (idx < E_) ? bq[idx] * scale : bk[idx - E_];
    bqk[idx] = bv;
  }
}

// ================= 256x256 8-phase GEMM =================
#define READ_A(pp, ha) do {                                                    \
  const int rbase = (pp) * 32768 + aRow + (ha) * 4096;                         \
  _Pragma("unroll") for (int m = 0; m < 4; ++m) {                              \
    aA[m][0] = *reinterpret_cast<const bf16x8*>(&sm[rbase + m * 1024 + aCol0]);\
    aA[m][1] = *reinterpret_cast<const bf16x8*>(&sm[rbase + m * 1024 + aCol1]);\
  } } while (0)

#define READ_B(pp, hb) do {                                                    \
  const int rbase = (pp) * 32768 + bRow + (hb) * 2048;                         \
  _Pragma("unroll") for (int n = 0; n < 2; ++n) {                              \
    bB[hb][n][0] = *reinterpret_cast<const bf16x8*>(&sm[rbase + n * 1024 + aCol0]);\
    bB[hb][n][1] = *reinterpret_cast<const bf16x8*>(&sm[rbase + n * 1024 + aCol1]);\
  } } while (0)

#define MFMA_Q(ha, hb) do {                                                    \
  _Pragma("unroll") for (int m = 0; m < 4; ++m)                                \
  _Pragma("unroll") for (int n = 0; n < 2; ++n) {                              \
    acc[(ha)*4+m][(hb)*2+n] = __builtin_amdgcn_mfma_f32_16x16x32_bf16(         \
        aA[m][0], bB[hb][n][0], acc[(ha)*4+m][(hb)*2+n], 0, 0, 0);             \
    acc[(ha)*4+m][(hb)*2+n] = __builtin_amdgcn_mfma_f32_16x16x32_bf16(         \
        aA[m][1], bB[hb][n][1], acc[(ha)*4+m][(hb)*2+n], 0, 0, 0);             \
  } } while (0)

#define STAGE_OP(gptr, ld, base, kt) do {                                      \
  _Pragma("unroll") for (int h = 0; h < 2; ++h)                                \
  _Pragma("unroll") for (int rr2 = 0; rr2 < 2; ++rr2)                          \
    gload_lds16(gptr + (long long)(h * 128 + rr2 * 64) * (ld) + (long long)(kt) * 64, \
                &sm[(base) + h * 8192 + rr2 * 4096 + wv * 512]);               \
  } while (0)

template<int OUT_BF16, int DO_EXP>
__global__ __launch_bounds__(512)
void gemm256(const unsigned short* __restrict__ A, int lda, long long strA,
             const unsigned short* __restrict__ B, int ldb, long long strB,
             void* __restrict__ Cv, int ldc, long long strC,
             int K, const float* __restrict__ bias, int NBX, int NBY,
             float* __restrict__ Rg)
{
  __shared__ unsigned short sm[65536];
  const int tid  = threadIdx.x;
  const int lane = tid & 63;
  const int wv   = tid >> 6;
  const int wr   = wv >> 2;
  const int wc   = wv & 3;
  const int fr   = lane & 15;

  const int nwg = gridDim.x, bid = blockIdx.x;
  const int qq = nwg >> 3, rr = nwg & 7, xc = bid & 7, ii = bid >> 3;
  const int wg = (xc < rr ? xc * (qq + 1) : rr * (qq + 1) + (xc - rr) * qq) + ii;
  const int bx = wg % NBX;
  const int tt = wg / NBX;
  const int by = tt % NBY;
  const int bz = tt / NBY;

  const long long m0 = (long long)by * 256;
  const long long n0 = (long long)bx * 256;
  const unsigned short* Ab = A + (long long)bz * strA + m0 * lda;
  const unsigned short* Bb = B + (long long)bz * strB + n0 * ldb;

  const int srow = tid >> 3;
  const int scol = ((tid & 7) * 8) ^ ((srow & 7) << 3);
  const unsigned short* gA = Ab + (long long)srow * lda + scol;
  const unsigned short* gB = Bb + (long long)srow * ldb + scol;

  const int xorc  = (fr & 7) << 3;
  const int q8    = (lane >> 4) * 8;
  const int aCol0 = (q8) ^ xorc;
  const int aCol1 = (32 + q8) ^ xorc;
  const int aRow  = (wr * 128 + fr) * 64;
  const int bRow  = 16384 + (wc * 64 + fr) * 64;

  f32x4 acc[8][4];
#pragma unroll
  for (int i = 0; i < 8; ++i)
#pragma unroll
    for (int j = 0; j < 4; ++j) acc[i][j] = (f32x4){0.f, 0.f, 0.f, 0.f};

  bf16x8 aA[4][2], bB[2][2][2];
  const int NT = K >> 6;

  STAGE_OP(gA, lda, 0, 0);
  STAGE_OP(gB, ldb, 16384, 0);
  asm volatile("s_waitcnt vmcnt(0)" ::: "memory");
  __builtin_amdgcn_s_barrier();

  int p = 0;
  for (int kt = 0; kt < NT; ++kt) {
    const int pn = p ^ 1;
    const int pnb = pn * 32768;
    READ_A(p, 0);
    READ_B(p, 0);
    if (kt + 1 < NT) STAGE_OP(gA, lda, pnb, kt + 1);
    __builtin_amdgcn_s_barrier();
    __builtin_amdgcn_s_setprio(1); MFMA_Q(0, 0); __builtin_amdgcn_s_setprio(0);
    __builtin_amdgcn_s_barrier();
    READ_B(p, 1);
    if (kt + 1 < NT) STAGE_OP(gB, ldb, pnb + 16384, kt + 1);
    __builtin_amdgcn_s_barrier();
    __builtin_amdgcn_s_setprio(1); MFMA_Q(0, 1); __builtin_amdgcn_s_setprio(0);
    __builtin_amdgcn_s_barrier();
    READ_A(p, 1);
    __builtin_amdgcn_s_barrier();
    __builtin_amdgcn_s_setprio(1); MFMA_Q(1, 0); __builtin_amdgcn_s_setprio(0);
    __builtin_amdgcn_s_barrier();
    __builtin_amdgcn_s_setprio(1); MFMA_Q(1, 1); __builtin_amdgcn_s_setprio(0);
    asm volatile("s_waitcnt vmcnt(0)" ::: "memory");
    __builtin_amdgcn_s_barrier();
    p = pn;
  }

  const int rq = (lane >> 4) * 4;
  if (bias) {
#pragma unroll
    for (int nn = 0; nn < 4; ++nn) {
      const float bv = bias[n0 + wc * 64 + (nn >> 1) * 32 + (nn & 1) * 16 + fr];
#pragma unroll
      for (int mm = 0; mm < 8; ++mm)
#pragma unroll
        for (int j = 0; j < 4; ++j) acc[mm][nn][j] += bv;
    }
  }
  if (DO_EXP) {
#pragma unroll
    for (int mm = 0; mm < 8; ++mm)
#pragma unroll
      for (int nn = 0; nn < 4; ++nn)
#pragma unroll
        for (int j = 0; j < 4; ++j) acc[mm][nn][j] = __expf(acc[mm][nn][j]);
  }
  if (OUT_BF16) {
    unsigned short* C = (unsigned short*)Cv + (long long)bz * strC;
#pragma unroll
    for (int mm = 0; mm < 8; ++mm)
#pragma unroll
      for (int j = 0; j < 4; ++j) {
        const long long row = m0 + wr * 128 + (mm >> 2) * 64 + (mm & 3) * 16 + rq + j;
#pragma unroll
        for (int nn = 0; nn < 4; ++nn) {
          const long long col = n0 + wc * 64 + (nn >> 1) * 32 + (nn & 1) * 16 + fr;
          C[row * ldc + col] = f2bf(acc[mm][nn][j]);
        }
      }
  } else {
    float* C = (float*)Cv + (long long)bz * strC;
#pragma unroll
    for (int mm = 0; mm < 8; ++mm)
#pragma unroll
      for (int j = 0; j < 4; ++j) {
        const long long row = m0 + wr * 128 + (mm >> 2) * 64 + (mm & 3) * 16 + rq + j;
#pragma unroll
        for (int nn = 0; nn < 4; ++nn) {
          const long long col = n0 + wc * 64 + (nn >> 1) * 32 + (nn & 1) * 16 + fr;
          C[row * ldc + col] = acc[mm][nn][j];
        }
      }
  }
  if (DO_EXP) {
    // partial row sums over this block's 256 cols -> Rg[(bz*NBX+bx)*2048 + m0 + lrow]
    float* rps = (float*)sm;       // [4 wc][256]
    __syncthreads();
#pragma unroll
    for (int mm = 0; mm < 8; ++mm)
#pragma unroll
      for (int j = 0; j < 4; ++j) {
        float s = acc[mm][0][j] + acc[mm][1][j] + acc[mm][2][j] + acc[mm][3][j];
        s += __shfl_xor(s, 1); s += __shfl_xor(s, 2);
        s += __shfl_xor(s, 4); s += __shfl_xor(s, 8);
        const int lrow = wr * 128 + (mm >> 2) * 64 + (mm & 3) * 16 + rq + j;
        if (fr == 0) rps[wc * 256 + lrow] = s;
      }
    __syncthreads();
    if (tid < 256) {
      const float s = rps[tid] + rps[256 + tid] + rps[512 + tid] + rps[768 + tid];
      Rg[((long long)bz * NBX + bx) * 2048 + m0 + tid] = s;
    }
  }
}

// ---------------- invR[b][t] = 1 / sum_c R[b][c][t]  (fixed order) ----------------
__global__ __launch_bounds__(256)
void rowsum_inv_kernel(const float* __restrict__ R, float* __restrict__ invR) {
  const int i = blockIdx.x * 256 + threadIdx.x;   // 0..16383
  const int b = i >> 11, t = i & 2047;
  float s = 0.f;
#pragma unroll
  for (int c = 0; c < 8; ++c) s += R[((long long)(b * 8 + c)) * 2048 + t];
  invR[i] = 1.0f / s;
}

// ================= PV GEMM: out = (P @ V) * invR =================
// BM=BN=128, BK=64, 4 waves (2M x 2N), wave tile 64x64, 64 KiB LDS -> 2 blocks/CU.
__global__ __launch_bounds__(256)
void gemm_pv2(const unsigned short* __restrict__ A, int lda, long long strA,
              const unsigned short* __restrict__ B, int ldb, long long strB,
              const float* __restrict__ invR,
              float* __restrict__ C, int ldc, long long strC, int K)
{
  __shared__ unsigned short sm[32768];   // 64 KiB: 2 bufs x (A 16KB + B 16KB)
  const int tid  = threadIdx.x;
  const int lane = tid & 63;
  const int wv   = tid >> 6;         // 0..3
  const int wrp  = wv >> 1;          // M half
  const int wcp  = wv & 1;           // N half
  const int fr   = lane & 15;

  // XCD swizzle; 512 blocks -> 64/XCD = one batch per XCD
  const int nwg = gridDim.x, bid = blockIdx.x;
  const int qq = nwg >> 3, rr = nwg & 7, xc = bid & 7, ii = bid >> 3;
  const int wg = (xc < rr ? xc * (qq + 1) : rr * (qq + 1) + (xc - rr) * qq) + ii;
  const int bx = wg & 3;             // N: 512/128
  const int by = (wg >> 2) & 15;     // M: 2048/128
  const int bz = wg >> 6;            // batch

  const long long m0 = (long long)by * 128;
  const long long n0 = (long long)bx * 128;
  const unsigned short* Ab = A + (long long)bz * strA + m0 * lda;
  const unsigned short* Bb = B + (long long)bz * strB + n0 * ldb;

  const int srow = tid >> 3;                                   // 0..31
  const int scol = ((tid & 7) * 8) ^ ((srow & 7) << 3);
  const unsigned short* gA = Ab + (long long)srow * lda + scol;
  const unsigned short* gB = Bb + (long long)srow * ldb + scol;

  const int xorc  = (fr & 7) << 3;
  const int q8    = (lane >> 4) * 8;
  const int c0    = q8 ^ xorc;
  const int c1    = (32 + q8) ^ xorc;
  const int aRow  = (wrp * 64 + fr) * 64;
  const int bRow  = 8192 + (wcp * 64 + fr) * 64;

  f32x4 acc[4][4];
#pragma unroll
  for (int i = 0; i < 4; ++i)
#pragma unroll
    for (int j = 0; j < 4; ++j) acc[i][j] = (f32x4){0.f, 0.f, 0.f, 0.f};

  bf16x8 aA[4][2], bB2[2][2];
  const int NT = K >> 6;

  // prologue: stage tile 0 into buffer 0
#pragma unroll
  for (int r = 0; r < 4; ++r)
    gload_lds16(gA + (long long)(r * 32) * lda, &sm[r * 2048 + tid * 8]);
#pragma unroll
  for (int r = 0; r < 4; ++r)
    gload_lds16(gB + (long long)(r * 32) * ldb, &sm[8192 + r * 2048 + tid * 8]);
  asm volatile("s_waitcnt vmcnt(0)" ::: "memory");
  __builtin_amdgcn_s_barrier();

  int p = 0;
  for (int kt = 0; kt < NT; ++kt) {
    const int pb = p * 16384, pnb = pb ^ 16384;
    const long long koff = (long long)(kt + 1) * 64;
    // ---- phase 0 ----
#pragma unroll
    for (int m = 0; m < 4; ++m) {
      aA[m][0] = *reinterpret_cast<const bf16x8*>(&sm[pb + aRow + m * 1024 + c0]);
      aA[m][1] = *reinterpret_cast<const bf16x8*>(&sm[pb + aRow + m * 1024 + c1]);
    }
#pragma unroll
    for (int n = 0; n < 2; ++n) {
      bB2[n][0] = *reinterpret_cast<const bf16x8*>(&sm[pb + bRow + n * 1024 + c0]);
      bB2[n][1] = *reinterpret_cast<const bf16x8*>(&sm[pb + bRow + n * 1024 + c1]);
    }
    if (kt + 1 < NT) {
#pragma unroll
      for (int r = 0; r < 4; ++r)
        gload_lds16(gA + (long long)(r * 32) * lda + koff, &sm[pnb + r * 2048 + tid * 8]);
    }
    __builtin_amdgcn_s_barrier();
    __builtin_amdgcn_s_setprio(1);
#pragma unroll
    for (int m = 0; m < 4; ++m)
#pragma unroll
      for (int n = 0; n < 2; ++n) {
        acc[m][n] = __builtin_amdgcn_mfma_f32_16x16x32_bf16(aA[m][0], bB2[n][0], acc[m][n], 0, 0, 0);
        acc[m][n] = __builtin_amdgcn_mfma_f32_16x16x32_bf16(aA[m][1], bB2[n][1], acc[m][n], 0, 0, 0);
      }
    __builtin_amdgcn_s_setprio(0);
    __builtin_amdgcn_s_barrier();
    // ---- phase 1 ----
#pragma unroll
    for (int n = 0; n < 2; ++n) {
      bB2[n][0] = *reinterpret_cast<const bf16x8*>(&sm[pb + bRow + (2 + n) * 1024 + c0]);
      bB2[n][1] = *reinterpret_cast<const bf16x8*>(&sm[pb + bRow + (2 + n) * 1024 + c1]);
    }
    if (kt + 1 < NT) {
#pragma unroll
      for (int r = 0; r < 4; ++r)
        gload_lds16(gB + (long long)(r * 32) * ldb + koff, &sm[pnb + 8192 + r * 2048 + tid * 8]);
    }
    __builtin_amdgcn_s_barrier();
    __builtin_amdgcn_s_setprio(1);
#pragma unroll
    for (int m = 0; m < 4; ++m)
#pragma unroll
      for (int n = 0; n < 2; ++n) {
        acc[m][2 + n] = __builtin_amdgcn_mfma_f32_16x16x32_bf16(aA[m][0], bB2[n][0], acc[m][2 + n], 0, 0, 0);
        acc[m][2 + n] = __builtin_amdgcn_mfma_f32_16x16x32_bf16(aA[m][1], bB2[n][1], acc[m][2 + n], 0, 0, 0);
      }
    __builtin_amdgcn_s_setprio(0);
    asm volatile("s_waitcnt vmcnt(0)" ::: "memory");
    __builtin_amdgcn_s_barrier();
    p ^= 1;
  }

  const int rq = (lane >> 4) * 4;
  float* Cb = C + (long long)bz * strC;
#pragma unroll
  for (int m = 0; m < 4; ++m)
#pragma unroll
    for (int j = 0; j < 4; ++j) {
      const int lrow = wrp * 64 + m * 16 + rq + j;
      const long long row = m0 + lrow;
      const float inv = invR[bz * 2048 + row];
#pragma unroll
      for (int n = 0; n < 4; ++n)
        Cb[row * ldc + n0 + wcp * 64 + n * 16 + fr] = acc[m][n][j] * inv;
    }
}

// ---------------- launch ----------------
extern "C" void kernel_launch(void* const* d_in, const int* in_sizes, int n_in,
                              void* d_out, int out_size, void* d_ws, size_t ws_size,
                              hipStream_t stream)
{
  const float* x  = (const float*)d_in[0];
  const float* Wq = (const float*)d_in[1];
  const float* bq = (const float*)d_in[2];
  const float* Wk = (const float*)d_in[3];
  const float* bk = (const float*)d_in[4];
  float* out = (float*)d_out;

  char* w = (char*)d_ws;
  unsigned short* xbf  = (unsigned short*)w;  w += (size_t)B_ * T_ * E_ * 2;
  unsigned short* xT   = (unsigned short*)w;  w += (size_t)B_ * T_ * E_ * 2;
  unsigned short* WT   = (unsigned short*)w;  w += (size_t)2 * E_ * E_ * 2;
  float*          bqk  = (float*)w;           w += (size_t)2 * E_ * 4;
  float*          R    = (float*)w;           w += (size_t)B_ * 8 * T_ * 4;      // 512 KB
  float*          invR = (float*)w;           w += (size_t)B_ * T_ * 4;          // 64 KB
  unsigned short* qk   = (unsigned short*)w;  w += (size_t)B_ * T_ * 2 * E_ * 2;
  unsigned short* attn = (unsigned short*)w;  w += (size_t)B_ * T_ * T_ * 2;

  const float scale = 0.044194173824159216f;  // 512^-0.5

  trans_conv_kernel<<<dim3(32, 8, 8), 256, 0, stream>>>(x, xbf, xT);
  conv_w_kernel<<<2048, 256, 0, stream>>>(Wq, Wk, bq, bk, WT, bqk, scale);

  // qk[16384, 1024] = xbf @ WT^T (+fused bias/scale)
  gemm256<1, 0><<<256, 512, 0, stream>>>(
      xbf, E_, 0, WT, E_, 0, qk, 2 * E_, 0, E_, bqk, 4, 64, nullptr);

  // P[b][2048,2048] = exp(q_b @ k_b^T), plus partial rowsums R[b][bx][row]
  gemm256<1, 1><<<512, 512, 0, stream>>>(
      qk, 2 * E_, (long long)T_ * 2 * E_,
      qk + E_, 2 * E_, (long long)T_ * 2 * E_,
      attn, T_, (long long)T_ * T_, E_, nullptr, 8, 8, R);

  rowsum_inv_kernel<<<64, 256, 0, stream>>>(R, invR);

  // out[b][2048,512] = (P_b @ x_b) * invR
  gemm_pv2<<<512, 256, 0, stream>>>(
      attn, T_, (long long)T_ * T_,
      xT, T_, (long long)E_ * T_,
      invR, out, E_, (long long)T_ * E_, T_);
}